// Round 1
// baseline (950.019 us; speedup 1.0000x reference)
//
#include <hip/hip_runtime.h>
#include <hip/hip_bf16.h>
#include <math.h>

#define EPSV 1e-5f

// ---------------------------------------------------------------- conv1
// x[2048,3,32,32] -> y1[2048,32,30,30] (bf16) + per-channel {sum,sumsq}
__global__ __launch_bounds__(256) void conv1_kernel(
    const float* __restrict__ x, const float* __restrict__ w,
    const float* __restrict__ bias, __hip_bfloat16* __restrict__ y1,
    float* __restrict__ sums) {
  __shared__ __align__(16) float xs[3072];   // 3*32*32
  __shared__ float wsm[864];                 // 32*3*3*3
  __shared__ float csum[32], css[32];
  const int n = blockIdx.x, tid = threadIdx.x, lane = tid & 63;
  const float4* xp = (const float4*)(x + (size_t)n * 3072);
  for (int i = tid; i < 768; i += 256) ((float4*)xs)[i] = xp[i];
  for (int i = tid; i < 864; i += 256) wsm[i] = w[i];
  if (tid < 32) { csum[tid] = 0.f; css[tid] = 0.f; }
  __syncthreads();
  for (int oc = 0; oc < 32; ++oc) {
    float wv[27];
#pragma unroll
    for (int k = 0; k < 27; ++k) wv[k] = wsm[oc * 27 + k];
    const float bo = bias[oc];
    float s = 0.f, ss = 0.f;
    for (int pix = tid; pix < 900; pix += 256) {
      const int i = pix / 30, j = pix - i * 30;
      const int base = i * 32 + j;
      float acc = bo;
#pragma unroll
      for (int c = 0; c < 3; ++c)
#pragma unroll
        for (int ki = 0; ki < 3; ++ki)
#pragma unroll
          for (int kj = 0; kj < 3; ++kj)
            acc += xs[c * 1024 + base + ki * 32 + kj] * wv[c * 9 + ki * 3 + kj];
      y1[(size_t)(n * 32 + oc) * 900 + pix] = __float2bfloat16(acc);
      s += acc; ss += acc * acc;
    }
#pragma unroll
    for (int off = 32; off; off >>= 1) { s += __shfl_down(s, off); ss += __shfl_down(ss, off); }
    if (lane == 0) { atomicAdd(&csum[oc], s); atomicAdd(&css[oc], ss); }
  }
  __syncthreads();
  if (tid < 32) { atomicAdd(&sums[tid], csum[tid]); atomicAdd(&sums[32 + tid], css[tid]); }
}

// ---------------------------------------------------------------- bn1+relu+pool1
// y1[2048,32,30,30] bf16 -> p1[2048,32,15,15] f32
__global__ __launch_bounds__(256) void bnpool1_kernel(
    const __hip_bfloat16* __restrict__ y1, const float* __restrict__ sums,
    const float* __restrict__ g, const float* __restrict__ bb,
    float* __restrict__ p1) {
  __shared__ float sc[32], sh[32];
  const int tid = threadIdx.x;
  if (tid < 32) {
    const float cnt = 2048.f * 900.f;
    const float mean = sums[tid] / cnt;
    const float var = sums[32 + tid] / cnt - mean * mean;
    const float s = g[tid] * rsqrtf(var + EPSV);
    sc[tid] = s; sh[tid] = bb[tid] - mean * s;
  }
  __syncthreads();
  const unsigned idx = blockIdx.x * 256u + tid;      // < 14745600, grid exact
  const unsigned j = idx % 15u; unsigned t = idx / 15u;
  const unsigned i = t % 15u; t /= 15u;
  const unsigned c = t & 31u; const unsigned n = t >> 5;
  const __hip_bfloat16* yp = y1 + (size_t)(n * 32 + c) * 900 + 60u * i + 2u * j;
  const unsigned r0 = *(const unsigned*)yp;
  const unsigned r1 = *(const unsigned*)(yp + 30);
  const float scl = sc[c], shf = sh[c];
  const float a = fmaxf(__uint_as_float(r0 << 16) * scl + shf, 0.f);
  const float b_ = fmaxf(__uint_as_float(r0 & 0xffff0000u) * scl + shf, 0.f);
  const float c_ = fmaxf(__uint_as_float(r1 << 16) * scl + shf, 0.f);
  const float d_ = fmaxf(__uint_as_float(r1 & 0xffff0000u) * scl + shf, 0.f);
  p1[idx] = (a + b_ + c_ + d_) * 0.25f;
}

// ---------------------------------------------------------------- conv2
// p1[2048,32,15,15] -> y2[2048,32,13,13] + stats. One oc per wave.
__global__ __launch_bounds__(256) void conv2_kernel(
    const float* __restrict__ p1, const float* __restrict__ w,
    const float* __restrict__ bias, float* __restrict__ y2,
    float* __restrict__ sums2) {
  __shared__ __align__(16) float xs[7200];    // 32*15*15
  __shared__ __align__(16) float wsm[9216];   // 32*32*3*3
  __shared__ float csum[32], css[32];
  const int n = blockIdx.x, tid = threadIdx.x;
  const int wave = tid >> 6, lane = tid & 63;
  const float4* xp = (const float4*)(p1 + (size_t)n * 7200);
  for (int i = tid; i < 1800; i += 256) ((float4*)xs)[i] = xp[i];
  for (int i = tid; i < 2304; i += 256) ((float4*)wsm)[i] = ((const float4*)w)[i];
  __syncthreads();
  const int p0 = lane, p1i = lane + 64, p2i = lane + 128;
  const int i0 = p0 / 13, j0 = p0 - 13 * i0;
  const int i1 = p1i / 13, j1 = p1i - 13 * i1;
  const int i2 = (p2i < 169) ? p2i / 13 : 0;
  const int j2 = (p2i < 169) ? p2i - 13 * ((p2i < 169) ? p2i / 13 : 0) : 0;
  const int b0 = i0 * 15 + j0, b1 = i1 * 15 + j1, b2 = i2 * 15 + j2;
  for (int ocb = 0; ocb < 8; ++ocb) {
    const int oc = ocb * 4 + wave;
    const float bo = bias[oc];
    float acc0 = bo, acc1 = bo, acc2 = bo;
    const float* wp = &wsm[oc * 288];
    for (int ic = 0; ic < 32; ++ic) {
      float wv[9];
#pragma unroll
      for (int k = 0; k < 9; ++k) wv[k] = wp[ic * 9 + k];
      const float* xc = &xs[ic * 225];
#pragma unroll
      for (int ki = 0; ki < 3; ++ki)
#pragma unroll
        for (int kj = 0; kj < 3; ++kj) {
          const float wk = wv[ki * 3 + kj];
          acc0 += xc[b0 + ki * 15 + kj] * wk;
          acc1 += xc[b1 + ki * 15 + kj] * wk;
          acc2 += xc[b2 + ki * 15 + kj] * wk;
        }
    }
    const size_t base = (size_t)(n * 32 + oc) * 169;
    float s = 0.f, ss = 0.f;
    y2[base + p0] = acc0; s += acc0; ss += acc0 * acc0;
    y2[base + p1i] = acc1; s += acc1; ss += acc1 * acc1;
    if (p2i < 169) { y2[base + p2i] = acc2; s += acc2; ss += acc2 * acc2; }
#pragma unroll
    for (int off = 32; off; off >>= 1) { s += __shfl_down(s, off); ss += __shfl_down(ss, off); }
    if (lane == 0) { csum[oc] = s; css[oc] = ss; }   // unique writer per oc
  }
  __syncthreads();
  if (tid < 32) { atomicAdd(&sums2[tid], csum[tid]); atomicAdd(&sums2[32 + tid], css[tid]); }
}

// ---------------------------------------------------------------- bn2+relu+pool2
// y2[2048,32,13,13] -> p2[2048,32,6,6]
__global__ __launch_bounds__(256) void bnpool2_kernel(
    const float* __restrict__ y2, const float* __restrict__ sums2,
    const float* __restrict__ g, const float* __restrict__ bb,
    float* __restrict__ p2) {
  __shared__ float sc[32], sh[32];
  const int tid = threadIdx.x;
  if (tid < 32) {
    const float cnt = 2048.f * 169.f;
    const float mean = sums2[tid] / cnt;
    const float var = sums2[32 + tid] / cnt - mean * mean;
    const float s = g[tid] * rsqrtf(var + EPSV);
    sc[tid] = s; sh[tid] = bb[tid] - mean * s;
  }
  __syncthreads();
  const unsigned idx = blockIdx.x * 256u + tid;     // < 2359296, grid exact
  const unsigned j = idx % 6u; unsigned t = idx / 6u;
  const unsigned i = t % 6u; t /= 6u;
  const unsigned c = t & 31u; const unsigned n = t >> 5;
  const float* yp = y2 + (size_t)(n * 32 + c) * 169 + 26u * i + 2u * j;
  const float scl = sc[c], shf = sh[c];
  const float a = fmaxf(yp[0] * scl + shf, 0.f);
  const float b_ = fmaxf(yp[1] * scl + shf, 0.f);
  const float c_ = fmaxf(yp[13] * scl + shf, 0.f);
  const float d_ = fmaxf(yp[14] * scl + shf, 0.f);
  p2[idx] = (a + b_ + c_ + d_) * 0.25f;
}

// ---------------------------------------------------------------- conv3
// p2[2048,32,6,6] -> y3[2048,32,4,4] + stats
__global__ __launch_bounds__(256) void conv3_kernel(
    const float* __restrict__ p2, const float* __restrict__ w,
    const float* __restrict__ bias, float* __restrict__ y3,
    float* __restrict__ sums3) {
  __shared__ __align__(16) float xs[1152];    // 32*6*6
  __shared__ __align__(16) float wsm[9216];
  __shared__ float csum[32], css[32];
  const int n = blockIdx.x, tid = threadIdx.x;
  const float4* xp = (const float4*)(p2 + (size_t)n * 1152);
  for (int i = tid; i < 288; i += 256) ((float4*)xs)[i] = xp[i];
  for (int i = tid; i < 2304; i += 256) ((float4*)wsm)[i] = ((const float4*)w)[i];
  __syncthreads();
#pragma unroll
  for (int half = 0; half < 2; ++half) {
    const int t = tid + half * 256;          // 0..511
    const int oc = t >> 4, pix = t & 15, i = pix >> 2, j = pix & 3;
    float acc = bias[oc];
    const float* wp = &wsm[oc * 288];
    for (int ic = 0; ic < 32; ++ic) {
      const float* xc = &xs[ic * 36 + i * 6 + j];
#pragma unroll
      for (int ki = 0; ki < 3; ++ki)
#pragma unroll
        for (int kj = 0; kj < 3; ++kj)
          acc += xc[ki * 6 + kj] * wp[ic * 9 + ki * 3 + kj];
    }
    y3[(size_t)n * 512 + t] = acc;
    float s = acc, ss = acc * acc;
#pragma unroll
    for (int off = 8; off; off >>= 1) { s += __shfl_down(s, off); ss += __shfl_down(ss, off); }
    if ((tid & 15) == 0) { csum[oc] = s; css[oc] = ss; }  // unique writer per oc
  }
  __syncthreads();
  if (tid < 32) { atomicAdd(&sums3[tid], csum[tid]); atomicAdd(&sums3[32 + tid], css[tid]); }
}

// ---------------------------------------------------------------- bn3+relu+pool3
// y3[2048,32,4,4] -> h0[2048,128]
__global__ __launch_bounds__(256) void bnpool3_kernel(
    const float* __restrict__ y3, const float* __restrict__ sums3,
    const float* __restrict__ g, const float* __restrict__ bb,
    float* __restrict__ h0) {
  __shared__ float sc[32], sh[32];
  const int tid = threadIdx.x;
  if (tid < 32) {
    const float cnt = 2048.f * 16.f;
    const float mean = sums3[tid] / cnt;
    const float var = sums3[32 + tid] / cnt - mean * mean;
    const float s = g[tid] * rsqrtf(var + EPSV);
    sc[tid] = s; sh[tid] = bb[tid] - mean * s;
  }
  __syncthreads();
  const unsigned idx = blockIdx.x * 256u + tid;   // < 262144, grid exact
  const unsigned j = idx & 1u; unsigned t = idx >> 1;
  const unsigned i = t & 1u; t >>= 1;
  const unsigned c = t & 31u; const unsigned n = t >> 5;
  const float* yp = y3 + (size_t)(n * 32 + c) * 16 + 8u * i + 2u * j;
  const float scl = sc[c], shf = sh[c];
  const float a = fmaxf(yp[0] * scl + shf, 0.f);
  const float b_ = fmaxf(yp[1] * scl + shf, 0.f);
  const float c_ = fmaxf(yp[4] * scl + shf, 0.f);
  const float d_ = fmaxf(yp[5] * scl + shf, 0.f);
  h0[idx] = (a + b_ + c_ + d_) * 0.25f;
}

// ---------------------------------------------------------------- routed MLP + out + log_softmax
#define LDW 129
__global__ __launch_bounds__(128) void mlp_kernel(
    const float* __restrict__ h0, const float* __restrict__ traj,
    const float* __restrict__ eW, const float* __restrict__ eb,
    const float* __restrict__ oW, const float* __restrict__ ob,
    float* __restrict__ out) {
  __shared__ float wl[128 * LDW];
  __shared__ float h[128];
  __shared__ float red[128];
  const int nrow = blockIdx.x;               // 0..4095
  const int b = nrow >> 1, beam = nrow & 1;
  const int o = threadIdx.x;
  h[o] = h0[b * 128 + o];
  for (int d = 0; d < 3; ++d) {
    const float* op = traj + (size_t)((d * 2048 + b) * 2 + beam) * 4;
    const float v0 = op[0], v1 = op[1], v2 = op[2], v3 = op[3];
    int sel = 0; float mx = v0;
    if (v1 > mx) { mx = v1; sel = 1; }
    if (v2 > mx) { mx = v2; sel = 2; }
    if (v3 > mx) { mx = v3; sel = 3; }
    const float4* Wg = (const float4*)(eW + sel * 16384);
    __syncthreads();                         // wl/h safe to overwrite/stage
    for (int t = o; t < 4096; t += 128) {
      const float4 v = Wg[t];
      const int row = t >> 5, col = (t & 31) * 4;
      float* dst = &wl[row * LDW + col];
      dst[0] = v.x; dst[1] = v.y; dst[2] = v.z; dst[3] = v.w;
    }
    __syncthreads();
    float acc = eb[sel * 128 + o];
    const float* wr = &wl[o * LDW];
#pragma unroll 8
    for (int k = 0; k < 128; ++k) acc += h[k] * wr[k];
    if (d != 2) acc = fmaxf(acc, 0.f);
    __syncthreads();
    h[o] = acc;
  }
  __syncthreads();
  for (int t = o; t < 3200; t += 128) {      // stage out_W [100,128]
    const float4 v = ((const float4*)oW)[t];
    const int row = t >> 5, col = (t & 31) * 4;
    float* dst = &wl[row * LDW + col];
    dst[0] = v.x; dst[1] = v.y; dst[2] = v.z; dst[3] = v.w;
  }
  __syncthreads();
  float p = -INFINITY;
  if (o < 100) {
    p = ob[o];
    const float* wr = &wl[o * LDW];
#pragma unroll 8
    for (int k = 0; k < 128; ++k) p += h[k] * wr[k];
  }
  red[o] = p;
  __syncthreads();
  float mx = red[0];
  for (int k = 1; k < 100; ++k) mx = fmaxf(mx, red[k]);
  const float e = (o < 100) ? expf(p - mx) : 0.f;
  __syncthreads();
  red[o] = e;
  __syncthreads();
  float ssum = 0.f;
  for (int k = 0; k < 100; ++k) ssum += red[k];
  if (o < 100) out[(size_t)nrow * 100 + o] = p - mx - logf(ssum);
}

// ---------------------------------------------------------------- launch
extern "C" void kernel_launch(void* const* d_in, const int* in_sizes, int n_in,
                              void* d_out, int out_size, void* d_ws, size_t ws_size,
                              hipStream_t stream) {
  const float* x     = (const float*)d_in[0];
  const float* traj  = (const float*)d_in[1];
  const float* score = (const float*)d_in[2];
  const float* cw1 = (const float*)d_in[3];
  const float* cb1 = (const float*)d_in[4];
  const float* g1  = (const float*)d_in[5];
  const float* bb1 = (const float*)d_in[6];
  const float* cw2 = (const float*)d_in[7];
  const float* cb2 = (const float*)d_in[8];
  const float* g2  = (const float*)d_in[9];
  const float* bb2 = (const float*)d_in[10];
  const float* cw3 = (const float*)d_in[11];
  const float* cb3 = (const float*)d_in[12];
  const float* g3  = (const float*)d_in[13];
  const float* bb3 = (const float*)d_in[14];
  const float* eW  = (const float*)d_in[15];
  const float* eb  = (const float*)d_in[16];
  const float* oW  = (const float*)d_in[17];
  const float* ob  = (const float*)d_in[18];
  float* out = (float*)d_out;

  char* ws = (char*)d_ws;
  float* sums = (float*)ws;                                   // 192 floats (3 levels x {32 sum, 32 ss})
  const size_t Y1_OFF = 1024;                                  // bf16, 58,982,400 elems = 117,964,800 B
  const size_t P1_OFF = Y1_OFF + 117964800;                    // f32, 14,745,600 elems = 58,982,400 B
  __hip_bfloat16* y1 = (__hip_bfloat16*)(ws + Y1_OFF);
  float* p1 = (float*)(ws + P1_OFF);
  float* y2 = (float*)(ws + Y1_OFF);   // reuse (y1 dead after bnpool1)
  float* p2 = (float*)(ws + P1_OFF);   // reuse (p1 dead after conv2)
  float* y3 = (float*)(ws + Y1_OFF);   // reuse (y2 dead after bnpool2)
  float* h0 = (float*)(ws + P1_OFF);   // reuse (p2 dead after conv3)

  hipMemsetAsync(sums, 0, 256 * sizeof(float), stream);

  conv1_kernel<<<2048, 256, 0, stream>>>(x, cw1, cb1, y1, sums);
  bnpool1_kernel<<<57600, 256, 0, stream>>>(y1, sums, g1, bb1, p1);
  conv2_kernel<<<2048, 256, 0, stream>>>(p1, cw2, cb2, y2, sums + 64);
  bnpool2_kernel<<<9216, 256, 0, stream>>>(y2, sums + 64, g2, bb2, p2);
  conv3_kernel<<<2048, 256, 0, stream>>>(p2, cw3, cb3, y3, sums + 128);
  bnpool3_kernel<<<1024, 256, 0, stream>>>(y3, sums + 128, g3, bb3, h0);
  mlp_kernel<<<4096, 128, 0, stream>>>(h0, traj, eW, eb, oW, ob, out);
  hipMemcpyAsync(out + 409600, score, 4096 * sizeof(float),
                 hipMemcpyDeviceToDevice, stream);
}

// Round 2
// 371.449 us; speedup vs baseline: 2.5576x; 2.5576x over previous
//
#include <hip/hip_runtime.h>
#include <math.h>

typedef unsigned short us;
typedef short s16x8 __attribute__((ext_vector_type(8)));
typedef float f32x4 __attribute__((ext_vector_type(4)));

#define EPSV 1e-5f

static __device__ inline us f2bf(float f) {            // RNE f32->bf16 (finite inputs)
  union { float f; unsigned u; } v; v.f = f;
  unsigned r = v.u + 0x7fffu + ((v.u >> 16) & 1u);
  return (us)(r >> 16);
}
static __device__ inline float bflo(unsigned u) { return __uint_as_float(u << 16); }
static __device__ inline float bfhi(unsigned u) { return __uint_as_float(u & 0xffff0000u); }

// ---------------------------------------------------------------- conv1 (MFMA)
// x[2048,3,32,32] f32 -> y1t[2048,900,32] bf16 (channel-minor) + per-oc {sum,sumsq}
// GEMM: A[900pix, K=32(27 used)] @ B[K, 32oc]; im2col A built in 240-pixel chunks.
template<int G>
__device__ inline s16x8 im2col8(const float* xs, int oi, int oj) {
  s16x8 out;
#pragma unroll
  for (int j = 0; j < 8; ++j) {
    const int k = G * 8 + j;                 // compile-time
    float v = 0.f;
    if (k < 27) {
      const int c = k / 9, t = k % 9, ki = t / 3, kj = t % 3;
      v = xs[c * 1024 + (oi + ki) * 32 + (oj + kj)];
    }
    out[j] = (short)f2bf(v);
  }
  return out;
}

__global__ __launch_bounds__(256) void conv1_mfma(
    const float* __restrict__ x, const float* __restrict__ w1,
    const float* __restrict__ cb, us* __restrict__ y1t,
    float* __restrict__ gs) {
  __shared__ __align__(16) float xs[3072];     // [3][32][32]
  __shared__ __align__(16) us A[240][40];      // im2col chunk, pad->40 (80B stride)
  __shared__ __align__(16) us wt[32][40];      // [oc][k]
  __shared__ float csum[32], css[32];
  const int n = blockIdx.x, tid = threadIdx.x;
  const int wave = tid >> 6, lane = tid & 63;
  const int row16 = lane & 15, kg = lane >> 4;
  const float4* xp = (const float4*)(x + (size_t)n * 3072);
  for (int i = tid; i < 768; i += 256) ((float4*)xs)[i] = xp[i];
  for (int t = tid; t < 1024; t += 256) {
    const int oc = t >> 5, k = t & 31;
    wt[oc][k] = (k < 27) ? f2bf(w1[oc * 27 + k]) : (us)0;   // zero K-pad
  }
  if (tid < 32) { csum[tid] = 0.f; css[tid] = 0.f; }
  __syncthreads();
  const s16x8 bf0 = *(const s16x8*)&wt[row16][kg * 8];
  const s16x8 bf1 = *(const s16x8*)&wt[16 + row16][kg * 8];
  const float bias0 = cb[row16], bias1 = cb[16 + row16];
  float s0 = 0.f, ss0 = 0.f, s1 = 0.f, ss1 = 0.f;
  for (int chunk = 0; chunk < 4; ++chunk) {
    const int r0 = chunk * 8;
    const int nrows = (chunk == 3) ? 6 : 8;
    const int npix = nrows * 30;
    for (int e = tid; e < npix * 4; e += 256) {      // build A: 1 b128 write per elem
      const int pix = e >> 2, g = e & 3;
      const int opg = r0 * 30 + pix, oi = opg / 30, oj = opg - oi * 30;
      s16x8 tmp;
      switch (g) {
        case 0: tmp = im2col8<0>(xs, oi, oj); break;
        case 1: tmp = im2col8<1>(xs, oi, oj); break;
        case 2: tmp = im2col8<2>(xs, oi, oj); break;
        default: tmp = im2col8<3>(xs, oi, oj); break;
      }
      *(s16x8*)&A[pix][g * 8] = tmp;
    }
    __syncthreads();
    const int MT = (npix + 15) >> 4;
#pragma unroll
    for (int m = 0; m < 4; ++m) {
      const int mt = wave + 4 * m;
      if (mt >= MT) continue;
      int pixA = mt * 16 + row16; if (pixA >= npix) pixA = 0;     // clamp pad rows
      const s16x8 a = *(const s16x8*)&A[pixA][kg * 8];
      f32x4 acc0 = {bias0, bias0, bias0, bias0};
      f32x4 acc1 = {bias1, bias1, bias1, bias1};
      acc0 = __builtin_amdgcn_mfma_f32_16x16x32_bf16(a, bf0, acc0, 0, 0, 0);
      acc1 = __builtin_amdgcn_mfma_f32_16x16x32_bf16(a, bf1, acc1, 0, 0, 0);
#pragma unroll
      for (int r = 0; r < 4; ++r) {
        const int pixc = mt * 16 + kg * 4 + r;         // C/D: row=kg*4+r, col=row16
        if (pixc < npix) {
          const size_t o = ((size_t)n * 900 + (r0 * 30 + pixc)) * 32;
          y1t[o + row16] = f2bf(acc0[r]);
          y1t[o + 16 + row16] = f2bf(acc1[r]);
          s0 += acc0[r]; ss0 += acc0[r] * acc0[r];
          s1 += acc1[r]; ss1 += acc1[r] * acc1[r];
        }
      }
    }
    __syncthreads();                                   // A reused next chunk
  }
  s0 += __shfl_down(s0, 32); s0 += __shfl_down(s0, 16);
  ss0 += __shfl_down(ss0, 32); ss0 += __shfl_down(ss0, 16);
  s1 += __shfl_down(s1, 32); s1 += __shfl_down(s1, 16);
  ss1 += __shfl_down(ss1, 32); ss1 += __shfl_down(ss1, 16);
  if (lane < 16) {
    atomicAdd(&csum[row16], s0); atomicAdd(&css[row16], ss0);
    atomicAdd(&csum[16 + row16], s1); atomicAdd(&css[16 + row16], ss1);
  }
  __syncthreads();
  if (tid < 32) { atomicAdd(&gs[tid], csum[tid]); atomicAdd(&gs[32 + tid], css[tid]); }
}

// ---------------------------------------------------------------- conv2/conv3 (MFMA)
// pin[n][INPIX][32] f32 -> yout[n][NPIX][32] f32 + stats. Per-tap K=32 GEMMs, 9 taps.
template<int IH, int OH, int MTPW>
__global__ __launch_bounds__(256) void conv23_mfma(
    const float* __restrict__ pin, const float* __restrict__ w,
    const float* __restrict__ cb, float* __restrict__ yout,
    float* __restrict__ gs) {
  constexpr int INPIX = IH * IH, NPIX = OH * OH, MT = (NPIX + 15) / 16;
  __shared__ __align__(16) us xs_t[INPIX][40];     // [in_pix][ic], 80B stride
  __shared__ __align__(16) us wt[9][32][40];       // [tap][oc][ic]
  __shared__ float csum[32], css[32];
  const int n = blockIdx.x, tid = threadIdx.x;
  const int wave = tid >> 6, lane = tid & 63;
  const int row16 = lane & 15, kg = lane >> 4;
  const float* xp = pin + (size_t)n * (32 * INPIX);
  for (int i = tid; i < 32 * INPIX; i += 256) xs_t[i >> 5][i & 31] = f2bf(xp[i]);
  for (int t = tid; t < 9216; t += 256) {
    const int tap = t >> 10, oc = (t >> 5) & 31, ic = t & 31;
    wt[tap][oc][ic] = f2bf(w[oc * 288 + ic * 9 + tap]);
  }
  if (tid < 32) { csum[tid] = 0.f; css[tid] = 0.f; }
  __syncthreads();
  int inb[MTPW];
#pragma unroll
  for (int m = 0; m < MTPW; ++m) {
    int pixA = (wave + 4 * m) * 16 + row16;
    if (pixA >= NPIX) pixA = 0;                        // clamp pad rows (finite garbage)
    const int oi = pixA / OH, oj = pixA - oi * OH;
    inb[m] = oi * IH + oj;
  }
  const float bias0 = cb[row16], bias1 = cb[16 + row16];
  f32x4 acc[MTPW][2];
#pragma unroll
  for (int m = 0; m < MTPW; ++m) {
    acc[m][0] = {bias0, bias0, bias0, bias0};
    acc[m][1] = {bias1, bias1, bias1, bias1};
  }
#pragma unroll
  for (int tap = 0; tap < 9; ++tap) {
    const int ki = tap / 3, kj = tap % 3;              // compile-time
    const s16x8 bf0 = *(const s16x8*)&wt[tap][row16][kg * 8];
    const s16x8 bf1 = *(const s16x8*)&wt[tap][16 + row16][kg * 8];
#pragma unroll
    for (int m = 0; m < MTPW; ++m) {
      const s16x8 a = *(const s16x8*)&xs_t[inb[m] + ki * IH + kj][kg * 8];
      acc[m][0] = __builtin_amdgcn_mfma_f32_16x16x32_bf16(a, bf0, acc[m][0], 0, 0, 0);
      acc[m][1] = __builtin_amdgcn_mfma_f32_16x16x32_bf16(a, bf1, acc[m][1], 0, 0, 0);
    }
  }
  float s0 = 0.f, ss0 = 0.f, s1 = 0.f, ss1 = 0.f;
#pragma unroll
  for (int m = 0; m < MTPW; ++m) {
    const int mt = wave + 4 * m;
#pragma unroll
    for (int r = 0; r < 4; ++r) {
      const int pix = mt * 16 + kg * 4 + r;
      if (pix < NPIX) {
        const size_t o = ((size_t)n * NPIX + pix) * 32;
        const float v0 = acc[m][0][r], v1 = acc[m][1][r];
        yout[o + row16] = v0;
        yout[o + 16 + row16] = v1;
        s0 += v0; ss0 += v0 * v0; s1 += v1; ss1 += v1 * v1;
      }
    }
  }
  s0 += __shfl_down(s0, 32); s0 += __shfl_down(s0, 16);
  ss0 += __shfl_down(ss0, 32); ss0 += __shfl_down(ss0, 16);
  s1 += __shfl_down(s1, 32); s1 += __shfl_down(s1, 16);
  ss1 += __shfl_down(ss1, 32); ss1 += __shfl_down(ss1, 16);
  if (lane < 16) {
    atomicAdd(&csum[row16], s0); atomicAdd(&css[row16], ss0);
    atomicAdd(&csum[16 + row16], s1); atomicAdd(&css[16 + row16], ss1);
  }
  __syncthreads();
  if (tid < 32) { atomicAdd(&gs[tid], csum[tid]); atomicAdd(&gs[32 + tid], css[tid]); }
}

// ---------------------------------------------------------------- bn1+relu+pool1
// y1t[2048,900,32] bf16 -> p1t[2048,225,32] f32; thread = (n,opix,channel-pair)
__global__ __launch_bounds__(256) void bnpool1_k(
    const us* __restrict__ y1t, const float* __restrict__ gs,
    const float* __restrict__ g, const float* __restrict__ bb,
    float* __restrict__ p1t) {
  __shared__ float sc[32], sh[32];
  const int tid = threadIdx.x;
  if (tid < 32) {
    const float cnt = 2048.f * 900.f;
    const float mean = gs[tid] / cnt;
    const float var = gs[32 + tid] / cnt - mean * mean;
    const float s = g[tid] * rsqrtf(var + EPSV);
    sc[tid] = s; sh[tid] = bb[tid] - mean * s;
  }
  __syncthreads();
  const unsigned idx = blockIdx.x * 256u + tid;   // < 7,372,800 exact
  const unsigned cp = idx & 15u; const unsigned q = idx >> 4;
  const unsigned opix = q % 225u, n = q / 225u;
  const unsigned oi = opix / 15u, oj = opix - oi * 15u;
  const size_t base = ((size_t)n * 900 + oi * 60 + oj * 2) * 32 + cp * 2;
  const unsigned r00 = *(const unsigned*)(y1t + base);
  const unsigned r01 = *(const unsigned*)(y1t + base + 32);
  const unsigned r10 = *(const unsigned*)(y1t + base + 960);
  const unsigned r11 = *(const unsigned*)(y1t + base + 992);
  const unsigned c0 = cp * 2u;
  const float sc0 = sc[c0], sh0 = sh[c0], sc1 = sc[c0 + 1], sh1 = sh[c0 + 1];
  const float o0 = (fmaxf(bflo(r00) * sc0 + sh0, 0.f) + fmaxf(bflo(r01) * sc0 + sh0, 0.f) +
                    fmaxf(bflo(r10) * sc0 + sh0, 0.f) + fmaxf(bflo(r11) * sc0 + sh0, 0.f)) * 0.25f;
  const float o1 = (fmaxf(bfhi(r00) * sc1 + sh1, 0.f) + fmaxf(bfhi(r01) * sc1 + sh1, 0.f) +
                    fmaxf(bfhi(r10) * sc1 + sh1, 0.f) + fmaxf(bfhi(r11) * sc1 + sh1, 0.f)) * 0.25f;
  *(float2*)(p1t + ((size_t)n * 225 + opix) * 32 + c0) = make_float2(o0, o1);
}

// ---------------------------------------------------------------- bn2+relu+pool2
// y2t[2048,169,32] -> p2t[2048,36,32]
__global__ __launch_bounds__(256) void bnpool2_k(
    const float* __restrict__ y2t, const float* __restrict__ gs,
    const float* __restrict__ g, const float* __restrict__ bb,
    float* __restrict__ p2t) {
  __shared__ float sc[32], sh[32];
  const int tid = threadIdx.x;
  if (tid < 32) {
    const float cnt = 2048.f * 169.f;
    const float mean = gs[tid] / cnt;
    const float var = gs[32 + tid] / cnt - mean * mean;
    const float s = g[tid] * rsqrtf(var + EPSV);
    sc[tid] = s; sh[tid] = bb[tid] - mean * s;
  }
  __syncthreads();
  const unsigned idx = blockIdx.x * 256u + tid;   // < 2,359,296 exact
  const unsigned c = idx & 31u; const unsigned q = idx >> 5;
  const unsigned opix = q % 36u, n = q / 36u;
  const unsigned oi = opix / 6u, oj = opix - oi * 6u;
  const float* yp = y2t + ((size_t)n * 169 + oi * 26 + oj * 2) * 32 + c;
  const float scl = sc[c], shf = sh[c];
  const float a = fmaxf(yp[0] * scl + shf, 0.f);
  const float b_ = fmaxf(yp[32] * scl + shf, 0.f);
  const float c_ = fmaxf(yp[416] * scl + shf, 0.f);
  const float d_ = fmaxf(yp[448] * scl + shf, 0.f);
  p2t[((size_t)n * 36 + opix) * 32 + c] = (a + b_ + c_ + d_) * 0.25f;
}

// ---------------------------------------------------------------- bn3+relu+pool3
// y3t[2048,16,32] -> h0[2048,128] in reference order (c*4 + i*2 + j)
__global__ __launch_bounds__(256) void bnpool3_k(
    const float* __restrict__ y3t, const float* __restrict__ gs,
    const float* __restrict__ g, const float* __restrict__ bb,
    float* __restrict__ h0) {
  __shared__ float sc[32], sh[32];
  const int tid = threadIdx.x;
  if (tid < 32) {
    const float cnt = 2048.f * 16.f;
    const float mean = gs[tid] / cnt;
    const float var = gs[32 + tid] / cnt - mean * mean;
    const float s = g[tid] * rsqrtf(var + EPSV);
    sc[tid] = s; sh[tid] = bb[tid] - mean * s;
  }
  __syncthreads();
  const unsigned idx = blockIdx.x * 256u + tid;   // < 262,144 exact
  const unsigned rem = idx & 127u, n = idx >> 7;
  const unsigned c = rem >> 2, op = rem & 3u, oi = op >> 1, oj = op & 1u;
  const float* yp = y3t + ((size_t)n * 16 + oi * 8 + oj * 2) * 32 + c;
  const float scl = sc[c], shf = sh[c];
  const float a = fmaxf(yp[0] * scl + shf, 0.f);
  const float b_ = fmaxf(yp[32] * scl + shf, 0.f);
  const float c_ = fmaxf(yp[128] * scl + shf, 0.f);
  const float d_ = fmaxf(yp[160] * scl + shf, 0.f);
  h0[(size_t)n * 128 + c * 4 + op] = (a + b_ + c_ + d_) * 0.25f;
}

// ---------------------------------------------------------------- routed MLP + out + log_softmax
#define LDW 129
__global__ __launch_bounds__(128) void mlp_kernel(
    const float* __restrict__ h0, const float* __restrict__ traj,
    const float* __restrict__ eW, const float* __restrict__ eb,
    const float* __restrict__ oW, const float* __restrict__ ob,
    float* __restrict__ out) {
  __shared__ float wl[128 * LDW];
  __shared__ float h[128];
  __shared__ float red[128];
  const int nrow = blockIdx.x;               // 0..4095
  const int b = nrow >> 1, beam = nrow & 1;
  const int o = threadIdx.x;
  h[o] = h0[b * 128 + o];
  for (int d = 0; d < 3; ++d) {
    const float* op = traj + (size_t)((d * 2048 + b) * 2 + beam) * 4;
    const float v0 = op[0], v1 = op[1], v2 = op[2], v3 = op[3];
    int sel = 0; float mx = v0;
    if (v1 > mx) { mx = v1; sel = 1; }
    if (v2 > mx) { mx = v2; sel = 2; }
    if (v3 > mx) { mx = v3; sel = 3; }
    const float4* Wg = (const float4*)(eW + sel * 16384);
    __syncthreads();
    for (int t = o; t < 4096; t += 128) {
      const float4 v = Wg[t];
      const int row = t >> 5, col = (t & 31) * 4;
      float* dst = &wl[row * LDW + col];
      dst[0] = v.x; dst[1] = v.y; dst[2] = v.z; dst[3] = v.w;
    }
    __syncthreads();
    float acc = eb[sel * 128 + o];
    const float* wr = &wl[o * LDW];
#pragma unroll 8
    for (int k = 0; k < 128; ++k) acc += h[k] * wr[k];
    if (d != 2) acc = fmaxf(acc, 0.f);
    __syncthreads();
    h[o] = acc;
  }
  __syncthreads();
  for (int t = o; t < 3200; t += 128) {
    const float4 v = ((const float4*)oW)[t];
    const int row = t >> 5, col = (t & 31) * 4;
    float* dst = &wl[row * LDW + col];
    dst[0] = v.x; dst[1] = v.y; dst[2] = v.z; dst[3] = v.w;
  }
  __syncthreads();
  float p = -INFINITY;
  if (o < 100) {
    p = ob[o];
    const float* wr = &wl[o * LDW];
#pragma unroll 8
    for (int k = 0; k < 128; ++k) p += h[k] * wr[k];
  }
  red[o] = p;
  __syncthreads();
  float mx = red[0];
  for (int k = 1; k < 100; ++k) mx = fmaxf(mx, red[k]);
  const float e = (o < 100) ? expf(p - mx) : 0.f;
  __syncthreads();
  red[o] = e;
  __syncthreads();
  float ssum = 0.f;
  for (int k = 0; k < 100; ++k) ssum += red[k];
  if (o < 100) out[(size_t)nrow * 100 + o] = p - mx - logf(ssum);
}

// ---------------------------------------------------------------- launch
extern "C" void kernel_launch(void* const* d_in, const int* in_sizes, int n_in,
                              void* d_out, int out_size, void* d_ws, size_t ws_size,
                              hipStream_t stream) {
  const float* x     = (const float*)d_in[0];
  const float* traj  = (const float*)d_in[1];
  const float* score = (const float*)d_in[2];
  const float* cw1 = (const float*)d_in[3];
  const float* cb1 = (const float*)d_in[4];
  const float* g1  = (const float*)d_in[5];
  const float* bb1 = (const float*)d_in[6];
  const float* cw2 = (const float*)d_in[7];
  const float* cb2 = (const float*)d_in[8];
  const float* g2  = (const float*)d_in[9];
  const float* bb2 = (const float*)d_in[10];
  const float* cw3 = (const float*)d_in[11];
  const float* cb3 = (const float*)d_in[12];
  const float* g3  = (const float*)d_in[13];
  const float* bb3 = (const float*)d_in[14];
  const float* eW  = (const float*)d_in[15];
  const float* eb  = (const float*)d_in[16];
  const float* oW  = (const float*)d_in[17];
  const float* ob  = (const float*)d_in[18];
  float* out = (float*)d_out;

  char* ws = (char*)d_ws;
  float* sums = (float*)ws;                       // 192 f32 used
  const size_t A_OFF = 1024;                       // big region
  const size_t B_OFF = A_OFF + 117964800;          // second region
  us*    y1t = (us*)(ws + A_OFF);                  // bf16 [2048,900,32] = 118MB
  float* p1t = (float*)(ws + B_OFF);               // f32 [2048,225,32] = 59MB
  float* y2t = (float*)(ws + A_OFF);               // f32 [2048,169,32] (y1t dead)
  float* p2t = (float*)(ws + B_OFF);               // f32 [2048,36,32]  (p1t dead)
  float* y3t = (float*)(ws + A_OFF);               // f32 [2048,16,32]  (y2t dead)
  float* h0  = (float*)(ws + B_OFF);               // f32 [2048,128]    (p2t dead)

  hipMemsetAsync(sums, 0, 256 * sizeof(float), stream);

  conv1_mfma<<<2048, 256, 0, stream>>>(x, cw1, cb1, y1t, sums);
  bnpool1_k<<<28800, 256, 0, stream>>>(y1t, sums, g1, bb1, p1t);
  conv23_mfma<15, 13, 3><<<2048, 256, 0, stream>>>(p1t, cw2, cb2, y2t, sums + 64);
  bnpool2_k<<<9216, 256, 0, stream>>>(y2t, sums + 64, g2, bb2, p2t);
  conv23_mfma<6, 4, 1><<<2048, 256, 0, stream>>>(p2t, cw3, cb3, y3t, sums + 128);
  bnpool3_k<<<1024, 256, 0, stream>>>(y3t, sums + 128, g3, bb3, h0);
  mlp_kernel<<<4096, 128, 0, stream>>>(h0, traj, eW, eb, oW, ob, out);
  hipMemcpyAsync(out + 409600, score, 4096 * sizeof(float),
                 hipMemcpyDeviceToDevice, stream);
}

// Round 3
// 281.477 us; speedup vs baseline: 3.3751x; 1.3196x over previous
//
#include <hip/hip_runtime.h>
#include <math.h>

typedef unsigned short us;
typedef short s16x8 __attribute__((ext_vector_type(8)));
typedef float f32x4 __attribute__((ext_vector_type(4)));

#define EPSV 1e-5f

static __device__ inline us f2bf(float f) {            // RNE f32->bf16 (finite inputs)
  union { float f; unsigned u; } v; v.f = f;
  unsigned r = v.u + 0x7fffu + ((v.u >> 16) & 1u);
  return (us)(r >> 16);
}
static __device__ inline float bflo(unsigned u) { return __uint_as_float(u << 16); }
static __device__ inline float bfhi(unsigned u) { return __uint_as_float(u & 0xffff0000u); }

// ---------------------------------------------------------------- conv1 (MFMA)
template<int G>
__device__ inline s16x8 im2col8(const float* xs, int oi, int oj) {
  s16x8 out;
#pragma unroll
  for (int j = 0; j < 8; ++j) {
    const int k = G * 8 + j;
    float v = 0.f;
    if (k < 27) {
      const int c = k / 9, t = k % 9, ki = t / 3, kj = t % 3;
      v = xs[c * 1024 + (oi + ki) * 32 + (oj + kj)];
    }
    out[j] = (short)f2bf(v);
  }
  return out;
}

__global__ __launch_bounds__(256) void conv1_mfma(
    const float* __restrict__ x, const float* __restrict__ w1,
    const float* __restrict__ cb, us* __restrict__ y1t,
    float* __restrict__ gs) {
  __shared__ __align__(16) float xs[3072];
  __shared__ __align__(16) us A[240][40];
  __shared__ __align__(16) us wt[32][40];
  __shared__ float csum[32], css[32];
  const int n = blockIdx.x, tid = threadIdx.x;
  const int wave = tid >> 6, lane = tid & 63;
  const int row16 = lane & 15, kg = lane >> 4;
  const float4* xp = (const float4*)(x + (size_t)n * 3072);
  for (int i = tid; i < 768; i += 256) ((float4*)xs)[i] = xp[i];
  for (int t = tid; t < 1024; t += 256) {
    const int oc = t >> 5, k = t & 31;
    wt[oc][k] = (k < 27) ? f2bf(w1[oc * 27 + k]) : (us)0;
  }
  if (tid < 32) { csum[tid] = 0.f; css[tid] = 0.f; }
  __syncthreads();
  const s16x8 bf0 = *(const s16x8*)&wt[row16][kg * 8];
  const s16x8 bf1 = *(const s16x8*)&wt[16 + row16][kg * 8];
  const float bias0 = cb[row16], bias1 = cb[16 + row16];
  float s0 = 0.f, ss0 = 0.f, s1 = 0.f, ss1 = 0.f;
  for (int chunk = 0; chunk < 4; ++chunk) {
    const int r0 = chunk * 8;
    const int nrows = (chunk == 3) ? 6 : 8;
    const int npix = nrows * 30;
    for (int e = tid; e < npix * 4; e += 256) {
      const int pix = e >> 2, g = e & 3;
      const int opg = r0 * 30 + pix, oi = opg / 30, oj = opg - oi * 30;
      s16x8 tmp;
      switch (g) {
        case 0: tmp = im2col8<0>(xs, oi, oj); break;
        case 1: tmp = im2col8<1>(xs, oi, oj); break;
        case 2: tmp = im2col8<2>(xs, oi, oj); break;
        default: tmp = im2col8<3>(xs, oi, oj); break;
      }
      *(s16x8*)&A[pix][g * 8] = tmp;
    }
    __syncthreads();
    const int MT = (npix + 15) >> 4;
#pragma unroll
    for (int m = 0; m < 4; ++m) {
      const int mt = wave + 4 * m;
      if (mt >= MT) continue;
      int pixA = mt * 16 + row16; if (pixA >= npix) pixA = 0;
      const s16x8 a = *(const s16x8*)&A[pixA][kg * 8];
      f32x4 acc0 = {bias0, bias0, bias0, bias0};
      f32x4 acc1 = {bias1, bias1, bias1, bias1};
      acc0 = __builtin_amdgcn_mfma_f32_16x16x32_bf16(a, bf0, acc0, 0, 0, 0);
      acc1 = __builtin_amdgcn_mfma_f32_16x16x32_bf16(a, bf1, acc1, 0, 0, 0);
#pragma unroll
      for (int r = 0; r < 4; ++r) {
        const int pixc = mt * 16 + kg * 4 + r;
        if (pixc < npix) {
          const size_t o = ((size_t)n * 900 + (r0 * 30 + pixc)) * 32;
          y1t[o + row16] = f2bf(acc0[r]);
          y1t[o + 16 + row16] = f2bf(acc1[r]);
          s0 += acc0[r]; ss0 += acc0[r] * acc0[r];
          s1 += acc1[r]; ss1 += acc1[r] * acc1[r];
        }
      }
    }
    __syncthreads();
  }
  s0 += __shfl_down(s0, 32); s0 += __shfl_down(s0, 16);
  ss0 += __shfl_down(ss0, 32); ss0 += __shfl_down(ss0, 16);
  s1 += __shfl_down(s1, 32); s1 += __shfl_down(s1, 16);
  ss1 += __shfl_down(ss1, 32); ss1 += __shfl_down(ss1, 16);
  if (lane < 16) {
    atomicAdd(&csum[row16], s0); atomicAdd(&css[row16], ss0);
    atomicAdd(&csum[16 + row16], s1); atomicAdd(&css[16 + row16], ss1);
  }
  __syncthreads();
  if (tid < 32) { atomicAdd(&gs[tid], csum[tid]); atomicAdd(&gs[32 + tid], css[tid]); }
}

// ---------------------------------------------------------------- conv2/conv3 (MFMA)
template<int IH, int OH, int MTPW>
__global__ __launch_bounds__(256) void conv23_mfma(
    const float* __restrict__ pin, const float* __restrict__ w,
    const float* __restrict__ cb, float* __restrict__ yout,
    float* __restrict__ gs) {
  constexpr int INPIX = IH * IH, NPIX = OH * OH;
  __shared__ __align__(16) us xs_t[INPIX][40];
  __shared__ __align__(16) us wt[9][32][40];
  __shared__ float csum[32], css[32];
  const int n = blockIdx.x, tid = threadIdx.x;
  const int wave = tid >> 6, lane = tid & 63;
  const int row16 = lane & 15, kg = lane >> 4;
  const float* xp = pin + (size_t)n * (32 * INPIX);
  for (int i = tid; i < 32 * INPIX; i += 256) xs_t[i >> 5][i & 31] = f2bf(xp[i]);
  for (int t = tid; t < 9216; t += 256) {
    const int tap = t >> 10, oc = (t >> 5) & 31, ic = t & 31;
    wt[tap][oc][ic] = f2bf(w[oc * 288 + ic * 9 + tap]);
  }
  if (tid < 32) { csum[tid] = 0.f; css[tid] = 0.f; }
  __syncthreads();
  int inb[MTPW];
#pragma unroll
  for (int m = 0; m < MTPW; ++m) {
    int pixA = (wave + 4 * m) * 16 + row16;
    if (pixA >= NPIX) pixA = 0;
    const int oi = pixA / OH, oj = pixA - oi * OH;
    inb[m] = oi * IH + oj;
  }
  const float bias0 = cb[row16], bias1 = cb[16 + row16];
  f32x4 acc[MTPW][2];
#pragma unroll
  for (int m = 0; m < MTPW; ++m) {
    acc[m][0] = {bias0, bias0, bias0, bias0};
    acc[m][1] = {bias1, bias1, bias1, bias1};
  }
#pragma unroll
  for (int tap = 0; tap < 9; ++tap) {
    const int ki = tap / 3, kj = tap % 3;
    const s16x8 bf0 = *(const s16x8*)&wt[tap][row16][kg * 8];
    const s16x8 bf1 = *(const s16x8*)&wt[tap][16 + row16][kg * 8];
#pragma unroll
    for (int m = 0; m < MTPW; ++m) {
      const s16x8 a = *(const s16x8*)&xs_t[inb[m] + ki * IH + kj][kg * 8];
      acc[m][0] = __builtin_amdgcn_mfma_f32_16x16x32_bf16(a, bf0, acc[m][0], 0, 0, 0);
      acc[m][1] = __builtin_amdgcn_mfma_f32_16x16x32_bf16(a, bf1, acc[m][1], 0, 0, 0);
    }
  }
  float s0 = 0.f, ss0 = 0.f, s1 = 0.f, ss1 = 0.f;
#pragma unroll
  for (int m = 0; m < MTPW; ++m) {
    const int mt = wave + 4 * m;
#pragma unroll
    for (int r = 0; r < 4; ++r) {
      const int pix = mt * 16 + kg * 4 + r;
      if (pix < NPIX) {
        const size_t o = ((size_t)n * NPIX + pix) * 32;
        const float v0 = acc[m][0][r], v1 = acc[m][1][r];
        yout[o + row16] = v0;
        yout[o + 16 + row16] = v1;
        s0 += v0; ss0 += v0 * v0; s1 += v1; ss1 += v1 * v1;
      }
    }
  }
  s0 += __shfl_down(s0, 32); s0 += __shfl_down(s0, 16);
  ss0 += __shfl_down(ss0, 32); ss0 += __shfl_down(ss0, 16);
  s1 += __shfl_down(s1, 32); s1 += __shfl_down(s1, 16);
  ss1 += __shfl_down(ss1, 32); ss1 += __shfl_down(ss1, 16);
  if (lane < 16) {
    atomicAdd(&csum[row16], s0); atomicAdd(&css[row16], ss0);
    atomicAdd(&csum[16 + row16], s1); atomicAdd(&css[16 + row16], ss1);
  }
  __syncthreads();
  if (tid < 32) { atomicAdd(&gs[tid], csum[tid]); atomicAdd(&gs[32 + tid], css[tid]); }
}

// ---------------------------------------------------------------- bnpool kernels
__global__ __launch_bounds__(256) void bnpool1_k(
    const us* __restrict__ y1t, const float* __restrict__ gs,
    const float* __restrict__ g, const float* __restrict__ bb,
    float* __restrict__ p1t) {
  __shared__ float sc[32], sh[32];
  const int tid = threadIdx.x;
  if (tid < 32) {
    const float cnt = 2048.f * 900.f;
    const float mean = gs[tid] / cnt;
    const float var = gs[32 + tid] / cnt - mean * mean;
    const float s = g[tid] * rsqrtf(var + EPSV);
    sc[tid] = s; sh[tid] = bb[tid] - mean * s;
  }
  __syncthreads();
  const unsigned idx = blockIdx.x * 256u + tid;
  const unsigned cp = idx & 15u; const unsigned q = idx >> 4;
  const unsigned opix = q % 225u, n = q / 225u;
  const unsigned oi = opix / 15u, oj = opix - oi * 15u;
  const size_t base = ((size_t)n * 900 + oi * 60 + oj * 2) * 32 + cp * 2;
  const unsigned r00 = *(const unsigned*)(y1t + base);
  const unsigned r01 = *(const unsigned*)(y1t + base + 32);
  const unsigned r10 = *(const unsigned*)(y1t + base + 960);
  const unsigned r11 = *(const unsigned*)(y1t + base + 992);
  const unsigned c0 = cp * 2u;
  const float sc0 = sc[c0], sh0 = sh[c0], sc1 = sc[c0 + 1], sh1 = sh[c0 + 1];
  const float o0 = (fmaxf(bflo(r00) * sc0 + sh0, 0.f) + fmaxf(bflo(r01) * sc0 + sh0, 0.f) +
                    fmaxf(bflo(r10) * sc0 + sh0, 0.f) + fmaxf(bflo(r11) * sc0 + sh0, 0.f)) * 0.25f;
  const float o1 = (fmaxf(bfhi(r00) * sc1 + sh1, 0.f) + fmaxf(bfhi(r01) * sc1 + sh1, 0.f) +
                    fmaxf(bfhi(r10) * sc1 + sh1, 0.f) + fmaxf(bfhi(r11) * sc1 + sh1, 0.f)) * 0.25f;
  *(float2*)(p1t + ((size_t)n * 225 + opix) * 32 + c0) = make_float2(o0, o1);
}

__global__ __launch_bounds__(256) void bnpool2_k(
    const float* __restrict__ y2t, const float* __restrict__ gs,
    const float* __restrict__ g, const float* __restrict__ bb,
    float* __restrict__ p2t) {
  __shared__ float sc[32], sh[32];
  const int tid = threadIdx.x;
  if (tid < 32) {
    const float cnt = 2048.f * 169.f;
    const float mean = gs[tid] / cnt;
    const float var = gs[32 + tid] / cnt - mean * mean;
    const float s = g[tid] * rsqrtf(var + EPSV);
    sc[tid] = s; sh[tid] = bb[tid] - mean * s;
  }
  __syncthreads();
  const unsigned idx = blockIdx.x * 256u + tid;
  const unsigned c = idx & 31u; const unsigned q = idx >> 5;
  const unsigned opix = q % 36u, n = q / 36u;
  const unsigned oi = opix / 6u, oj = opix - oi * 6u;
  const float* yp = y2t + ((size_t)n * 169 + oi * 26 + oj * 2) * 32 + c;
  const float scl = sc[c], shf = sh[c];
  const float a = fmaxf(yp[0] * scl + shf, 0.f);
  const float b_ = fmaxf(yp[32] * scl + shf, 0.f);
  const float c_ = fmaxf(yp[416] * scl + shf, 0.f);
  const float d_ = fmaxf(yp[448] * scl + shf, 0.f);
  p2t[((size_t)n * 36 + opix) * 32 + c] = (a + b_ + c_ + d_) * 0.25f;
}

__global__ __launch_bounds__(256) void bnpool3_k(
    const float* __restrict__ y3t, const float* __restrict__ gs,
    const float* __restrict__ g, const float* __restrict__ bb,
    float* __restrict__ h0) {
  __shared__ float sc[32], sh[32];
  const int tid = threadIdx.x;
  if (tid < 32) {
    const float cnt = 2048.f * 16.f;
    const float mean = gs[tid] / cnt;
    const float var = gs[32 + tid] / cnt - mean * mean;
    const float s = g[tid] * rsqrtf(var + EPSV);
    sc[tid] = s; sh[tid] = bb[tid] - mean * s;
  }
  __syncthreads();
  const unsigned idx = blockIdx.x * 256u + tid;
  const unsigned rem = idx & 127u, n = idx >> 7;
  const unsigned c = rem >> 2, op = rem & 3u, oi = op >> 1, oj = op & 1u;
  const float* yp = y3t + ((size_t)n * 16 + oi * 8 + oj * 2) * 32 + c;
  const float scl = sc[c], shf = sh[c];
  const float a = fmaxf(yp[0] * scl + shf, 0.f);
  const float b_ = fmaxf(yp[32] * scl + shf, 0.f);
  const float c_ = fmaxf(yp[128] * scl + shf, 0.f);
  const float d_ = fmaxf(yp[160] * scl + shf, 0.f);
  h0[(size_t)n * 128 + c * 4 + op] = (a + b_ + c_ + d_) * 0.25f;
}

// ---------------------------------------------------------------- MFMA routed MLP
// 64 blocks x 256 thr; wave owns 16 rows. Experts 0..2 via MFMA + per-row select,
// expert 3 (identity) taken from f32 C-layout registers (exact).
#define STR 136
__global__ __launch_bounds__(256) void mlp2_kernel(
    const float* __restrict__ h0, const float* __restrict__ traj,
    const float* __restrict__ eW, const float* __restrict__ eb,
    const float* __restrict__ oW, const float* __restrict__ ob,
    float* __restrict__ out) {
  __shared__ __align__(16) us wexp[3 * 128 * STR];   // [e][o][d]
  __shared__ __align__(16) us owl[112 * STR];        // [cls][d], zero-padded
  __shared__ __align__(16) us htile[4][16 * STR];    // per-wave h tile [row][d]
  __shared__ float ebl[384];
  __shared__ float obl[112];
  const int tid = threadIdx.x, wave = tid >> 6, lane = tid & 63;
  const int row16 = lane & 15, kg = lane >> 4;
  const int rbase = blockIdx.x * 64 + wave * 16;
  // stage expert weights (bf16)
  for (int i = tid; i < 12288; i += 256) {
    const int e = i >> 12, rem = i & 4095, o = rem >> 5, d4 = (rem & 31) * 4;
    const float4 v = *(const float4*)(eW + ((e * 128 + o) * 128 + d4));
    const unsigned lo = f2bf(v.x) | ((unsigned)f2bf(v.y) << 16);
    const unsigned hi = f2bf(v.z) | ((unsigned)f2bf(v.w) << 16);
    *(uint2*)&wexp[(e * 128 + o) * STR + d4] = make_uint2(lo, hi);
  }
  // stage out_W (bf16, zero-pad cls 100..111)
  for (int i = tid; i < 112 * 32; i += 256) {
    const int cls = i >> 5, d4 = (i & 31) * 4;
    float4 v = make_float4(0.f, 0.f, 0.f, 0.f);
    if (cls < 100) v = *(const float4*)(oW + cls * 128 + d4);
    const unsigned lo = f2bf(v.x) | ((unsigned)f2bf(v.y) << 16);
    const unsigned hi = f2bf(v.z) | ((unsigned)f2bf(v.w) << 16);
    *(uint2*)&owl[cls * STR + d4] = make_uint2(lo, hi);
  }
  for (int i = tid; i < 384; i += 256) ebl[i] = eb[i];
  if (tid < 112) obl[tid] = (tid < 100) ? ob[tid] : 0.f;
  // stage this wave's h tile from h0 (bf16)
  us* ht = &htile[wave][0];
  for (int i = lane; i < 256; i += 64) {
    const int row = i >> 4, d8 = (i & 15) * 8;
    const int rowg = rbase + row;
    const float4 v0 = *(const float4*)(h0 + (size_t)(rowg >> 1) * 128 + d8);
    const float4 v1 = *(const float4*)(h0 + (size_t)(rowg >> 1) * 128 + d8 + 4);
    uint4 p;
    p.x = f2bf(v0.x) | ((unsigned)f2bf(v0.y) << 16);
    p.y = f2bf(v0.z) | ((unsigned)f2bf(v0.w) << 16);
    p.z = f2bf(v1.x) | ((unsigned)f2bf(v1.y) << 16);
    p.w = f2bf(v1.z) | ((unsigned)f2bf(v1.w) << 16);
    *(uint4*)&ht[row * STR + d8] = p;
  }
  __syncthreads();
  // initial h in f32 C-layout registers (exact)
  float accv[8][4];
#pragma unroll
  for (int ct = 0; ct < 8; ++ct)
#pragma unroll
    for (int r = 0; r < 4; ++r) {
      const int rowg = rbase + kg * 4 + r;
      accv[ct][r] = h0[(size_t)(rowg >> 1) * 128 + ct * 16 + row16];
    }
  // three routed layers
  for (int d = 0; d < 3; ++d) {
    int sel[4];
#pragma unroll
    for (int r = 0; r < 4; ++r) {
      const int rowg = rbase + kg * 4 + r;
      const float4 t4 = *(const float4*)(traj + d * 16384 + rowg * 4);
      int s = 0; float mx = t4.x;
      if (t4.y > mx) { mx = t4.y; s = 1; }
      if (t4.z > mx) { mx = t4.z; s = 2; }
      if (t4.w > mx) { mx = t4.w; s = 3; }
      sel[r] = s;
    }
    s16x8 a[4];
#pragma unroll
    for (int kc = 0; kc < 4; ++kc)
      a[kc] = *(const s16x8*)&ht[row16 * STR + kc * 32 + kg * 8];
    float newacc[8][4];
#pragma unroll
    for (int ct = 0; ct < 8; ++ct)
#pragma unroll
      for (int r = 0; r < 4; ++r)
        newacc[ct][r] = (sel[r] == 3) ? accv[ct][r] : 0.f;
#pragma unroll
    for (int e = 0; e < 3; ++e) {
#pragma unroll
      for (int ct = 0; ct < 8; ++ct) {
        f32x4 t = {0.f, 0.f, 0.f, 0.f};
#pragma unroll
        for (int kc = 0; kc < 4; ++kc) {
          const s16x8 b = *(const s16x8*)&wexp[(e * 128 + ct * 16 + row16) * STR + kc * 32 + kg * 8];
          t = __builtin_amdgcn_mfma_f32_16x16x32_bf16(a[kc], b, t, 0, 0, 0);
        }
        const float bias = ebl[e * 128 + ct * 16 + row16];
#pragma unroll
        for (int r = 0; r < 4; ++r)
          if (sel[r] == e) newacc[ct][r] = t[r] + bias;
      }
    }
#pragma unroll
    for (int ct = 0; ct < 8; ++ct)
#pragma unroll
      for (int r = 0; r < 4; ++r) {
        float v = newacc[ct][r];
        if (d < 2) v = fmaxf(v, 0.f);
        accv[ct][r] = v;
        ht[(kg * 4 + r) * STR + ct * 16 + row16] = f2bf(v);   // same-wave LDS, in-order
      }
  }
  // output GEMM (100 classes in 7 col-tiles) + log_softmax
  s16x8 a[4];
#pragma unroll
  for (int kc = 0; kc < 4; ++kc)
    a[kc] = *(const s16x8*)&ht[row16 * STR + kc * 32 + kg * 8];
  float preds[7][4];
#pragma unroll
  for (int ct = 0; ct < 7; ++ct) {
    f32x4 t = {0.f, 0.f, 0.f, 0.f};
#pragma unroll
    for (int kc = 0; kc < 4; ++kc) {
      const s16x8 b = *(const s16x8*)&owl[(ct * 16 + row16) * STR + kc * 32 + kg * 8];
      t = __builtin_amdgcn_mfma_f32_16x16x32_bf16(a[kc], b, t, 0, 0, 0);
    }
    const float bias = obl[ct * 16 + row16];
#pragma unroll
    for (int r = 0; r < 4; ++r) preds[ct][r] = t[r] + bias;
  }
  const bool v6 = (96 + row16) < 100;      // ct==6 validity
#pragma unroll
  for (int r = 0; r < 4; ++r) {
    float mx = -INFINITY;
#pragma unroll
    for (int ct = 0; ct < 7; ++ct)
      if (ct < 6 || v6) mx = fmaxf(mx, preds[ct][r]);
    mx = fmaxf(mx, __shfl_xor(mx, 1)); mx = fmaxf(mx, __shfl_xor(mx, 2));
    mx = fmaxf(mx, __shfl_xor(mx, 4)); mx = fmaxf(mx, __shfl_xor(mx, 8));
    float s = 0.f;
#pragma unroll
    for (int ct = 0; ct < 7; ++ct)
      if (ct < 6 || v6) s += expf(preds[ct][r] - mx);
    s += __shfl_xor(s, 1); s += __shfl_xor(s, 2);
    s += __shfl_xor(s, 4); s += __shfl_xor(s, 8);
    const float lg = mx + logf(s);
    const int rowg = rbase + kg * 4 + r;
#pragma unroll
    for (int ct = 0; ct < 7; ++ct)
      if (ct < 6 || v6) out[(size_t)rowg * 100 + ct * 16 + row16] = preds[ct][r] - lg;
  }
}

// ---------------------------------------------------------------- launch
extern "C" void kernel_launch(void* const* d_in, const int* in_sizes, int n_in,
                              void* d_out, int out_size, void* d_ws, size_t ws_size,
                              hipStream_t stream) {
  const float* x     = (const float*)d_in[0];
  const float* traj  = (const float*)d_in[1];
  const float* score = (const float*)d_in[2];
  const float* cw1 = (const float*)d_in[3];
  const float* cb1 = (const float*)d_in[4];
  const float* g1  = (const float*)d_in[5];
  const float* bb1 = (const float*)d_in[6];
  const float* cw2 = (const float*)d_in[7];
  const float* cb2 = (const float*)d_in[8];
  const float* g2  = (const float*)d_in[9];
  const float* bb2 = (const float*)d_in[10];
  const float* cw3 = (const float*)d_in[11];
  const float* cb3 = (const float*)d_in[12];
  const float* g3  = (const float*)d_in[13];
  const float* bb3 = (const float*)d_in[14];
  const float* eW  = (const float*)d_in[15];
  const float* eb  = (const float*)d_in[16];
  const float* oW  = (const float*)d_in[17];
  const float* ob  = (const float*)d_in[18];
  float* out = (float*)d_out;

  char* ws = (char*)d_ws;
  float* sums = (float*)ws;
  const size_t A_OFF = 1024;
  const size_t B_OFF = A_OFF + 117964800;
  us*    y1t = (us*)(ws + A_OFF);
  float* p1t = (float*)(ws + B_OFF);
  float* y2t = (float*)(ws + A_OFF);
  float* p2t = (float*)(ws + B_OFF);
  float* y3t = (float*)(ws + A_OFF);
  float* h0  = (float*)(ws + B_OFF);

  hipMemsetAsync(sums, 0, 256 * sizeof(float), stream);

  conv1_mfma<<<2048, 256, 0, stream>>>(x, cw1, cb1, y1t, sums);
  bnpool1_k<<<28800, 256, 0, stream>>>(y1t, sums, g1, bb1, p1t);
  conv23_mfma<15, 13, 3><<<2048, 256, 0, stream>>>(p1t, cw2, cb2, y2t, sums + 64);
  bnpool2_k<<<9216, 256, 0, stream>>>(y2t, sums + 64, g2, bb2, p2t);
  conv23_mfma<6, 4, 1><<<2048, 256, 0, stream>>>(p2t, cw3, cb3, y3t, sums + 128);
  bnpool3_k<<<1024, 256, 0, stream>>>(y3t, sums + 128, g3, bb3, h0);
  mlp2_kernel<<<64, 256, 0, stream>>>(h0, traj, eW, eb, oW, ob, out);
  hipMemcpyAsync(out + 409600, score, 4096 * sizeof(float),
                 hipMemcpyDeviceToDevice, stream);
}